// Round 3
// baseline (209.085 us; speedup 1.0000x reference)
//
#include <hip/hip_runtime.h>

typedef unsigned short u16;
typedef short short8 __attribute__((ext_vector_type(8)));
typedef float f32x4 __attribute__((ext_vector_type(4)));

static_assert(sizeof(short8) == 16, "short8 must be 16B");

// ---------- helpers ----------
__device__ __forceinline__ u16 f2bf(float f) {
  unsigned u = __float_as_uint(f);
  u += 0x7FFFu + ((u >> 16) & 1u);   // RNE
  return (u16)(u >> 16);
}
__device__ __forceinline__ float bf2f(u16 h) { return __uint_as_float(((unsigned)h) << 16); }

__device__ __forceinline__ f32x4 mfma_bf16(short8 a, short8 b, f32x4 c) {
  return __builtin_amdgcn_mfma_f32_16x16x32_bf16(a, b, c, 0, 0, 0);
}

__device__ __forceinline__ void gload_lds16(const void* g, void* l) {
  __builtin_amdgcn_global_load_lds((__attribute__((address_space(1))) void*)g,
                                   (__attribute__((address_space(3))) void*)l, 16, 0, 0);
}

__device__ __forceinline__ float exp2v(float x) {
  float r; asm("v_exp_f32 %0, %1" : "=v"(r) : "v"(x)); return r;
}
__device__ __forceinline__ unsigned cvtpk(float lo, float hi) {
  unsigned r; asm("v_cvt_pk_bf16_f32 %0, %1, %2" : "=v"(r) : "v"(lo), "v"(hi)); return r;
}
__device__ __forceinline__ f32x4 vmax4(f32x4 a, f32x4 b) {
  f32x4 r;
  r[0] = fmaxf(a[0], b[0]); r[1] = fmaxf(a[1], b[1]);
  r[2] = fmaxf(a[2], b[2]); r[3] = fmaxf(a[3], b[3]);
  return r;
}

// ---------- fp32 -> bf16 conversion (hidden + 4 weights) ----------
__global__ __launch_bounds__(256) void cvt_kernel(
    const float* __restrict__ hs, const float* __restrict__ wq, const float* __restrict__ wk,
    const float* __restrict__ wv, const float* __restrict__ wo,
    u16* __restrict__ hbf, u16* __restrict__ wbf) {
  const float* src; u16* dst; int n4;
  switch (blockIdx.y) {
    case 0:  src = hs; dst = hbf;            n4 = 786432; break;  // 4096*768/4
    case 1:  src = wq; dst = wbf;            n4 = 147456; break;  // 768*768/4
    case 2:  src = wk; dst = wbf + 589824;   n4 = 147456; break;
    case 3:  src = wv; dst = wbf + 1179648;  n4 = 147456; break;
    default: src = wo; dst = wbf + 1769472;  n4 = 147456; break;
  }
  int i = blockIdx.x * 256 + threadIdx.x;
  if (i >= n4) return;
  float4 v = ((const float4*)src)[i];
  uint2 r;
  r.x = (unsigned)f2bf(v.x) | ((unsigned)f2bf(v.y) << 16);
  r.y = (unsigned)f2bf(v.z) | ((unsigned)f2bf(v.w) << 16);
  ((uint2*)dst)[i] = r;
}

// ---------- RoPE, in-place on q and k ([B*H, S, 64] bf16) ----------
__global__ __launch_bounds__(256) void rope_kernel(u16* __restrict__ qb, u16* __restrict__ kb) {
  int idx = blockIdx.x * 256 + threadIdx.x;   // < 24*2048*32 = 1572864
  u16* buf = blockIdx.y ? kb : qb;
  int j = idx & 31;
  int sbh = idx >> 5;                         // bh*2048 + s
  int s = sbh & 2047;
  size_t base = (size_t)sbh * 64;
  float x1 = bf2f(buf[base + j]);
  float x2 = bf2f(buf[base + 32 + j]);
  float freq = __expf(-0.2878231366242557f * (float)j);  // 10000^(-j/32)
  float th = (float)s * freq;
  float sn, cs;
  __sincosf(th, &sn, &cs);
  buf[base + j]      = f2bf(x1 * cs - x2 * sn);
  buf[base + 32 + j] = f2bf(x2 * cs + x1 * sn);
}

// ---------- GEMM: C(MxN) = A(MxK) * B(NxK)^T, bf16 in, m97-style ----------
// MODE 0: QKV epilogue -> q[B,H,S,D], k[B,H,S,D], vt[B,H,D,S] (bf16)
// MODE 1: fp32 epilogue -> fout row-major (M x 768)
template <int MODE>
__global__ __launch_bounds__(256) void gemm_bt(
    const u16* __restrict__ A, const u16* __restrict__ Bm,
    u16* __restrict__ qb, u16* __restrict__ kb, u16* __restrict__ vtb,
    float* __restrict__ fout) {
  __shared__ char sA[16384];   // 128 rows x 64 bf16 (8 x 16B slots, XOR-swizzled)
  __shared__ char sB[16384];
  const int K = 768;
  const int t = threadIdx.x;
  const int lane = t & 63;
  const int w = t >> 6;              // wave 0..3
  const int wr = w >> 1, wc = w & 1; // 2x2 wave grid of 64x64 subtiles
  const int lrow = lane & 15, lkg = lane >> 4;
  const int arow0 = blockIdx.x * 128, brow0 = blockIdx.y * 128;

  f32x4 acc[4][4];
  const f32x4 z4 = {0.f, 0.f, 0.f, 0.f};
#pragma unroll
  for (int m = 0; m < 4; ++m)
#pragma unroll
    for (int n = 0; n < 4; ++n) acc[m][n] = z4;

  const int srow = t >> 3;   // 0..31 (staging row within 32-row chunk)
  const int sslot = t & 7;   // physical 16B slot

  for (int kt = 0; kt < K; kt += 64) {
    __syncthreads();
#pragma unroll
    for (int it = 0; it < 4; ++it) {
      int r = it * 32 + srow;
      int ls = sslot ^ (r & 7);   // inverse-swizzled global source slot
      gload_lds16(A + (size_t)(arow0 + r) * K + (kt + ls * 8), sA + it * 4096 + w * 1024);
      gload_lds16(Bm + (size_t)(brow0 + r) * K + (kt + ls * 8), sB + it * 4096 + w * 1024);
    }
    __syncthreads();
#pragma unroll
    for (int kk = 0; kk < 2; ++kk) {
      short8 af[4], bfr[4];
#pragma unroll
      for (int m = 0; m < 4; ++m) {
        int row = wr * 64 + m * 16 + lrow;
        int ph = (kk * 4 + lkg) ^ (row & 7);
        af[m] = *(const short8*)(sA + row * 128 + ph * 16);
      }
#pragma unroll
      for (int n = 0; n < 4; ++n) {
        int row = wc * 64 + n * 16 + lrow;
        int ph = (kk * 4 + lkg) ^ (row & 7);
        bfr[n] = *(const short8*)(sB + row * 128 + ph * 16);
      }
#pragma unroll
      for (int m = 0; m < 4; ++m)
#pragma unroll
        for (int n = 0; n < 4; ++n) acc[m][n] = mfma_bf16(af[m], bfr[n], acc[m][n]);
    }
  }

#pragma unroll
  for (int m = 0; m < 4; ++m) {
#pragma unroll
    for (int n = 0; n < 4; ++n) {
#pragma unroll
      for (int i = 0; i < 4; ++i) {
        int row = arow0 + wr * 64 + m * 16 + (lane >> 4) * 4 + i;
        int col = brow0 + wc * 64 + n * 16 + (lane & 15);
        float v = acc[m][n][i];
        if (MODE == 1) {
          fout[(size_t)row * 768 + col] = v;
        } else {
          int b = row >> 11, s = row & 2047;
          int qsel = col / 768;            // uniform per block (768 % 128 == 0)
          int oc = col - qsel * 768;
          int h = oc >> 6, d = oc & 63;
          size_t bh = (size_t)(b * 12 + h);
          u16 bv = f2bf(v);
          if (qsel == 0)      qb[(bh * 2048 + s) * 64 + d] = bv;
          else if (qsel == 1) kb[(bh * 2048 + s) * 64 + d] = bv;
          else                vtb[(bh * 64 + d) * 2048 + s] = bv;  // V transposed
        }
      }
    }
  }
}

// ---------- causal flash attention v3 ----------
// Swapped QK^T (S^T in regs, q = lane&15) -> in-register softmax (2 cross-lane
// steps), lane-local P packing via custom kv-bijection matched by permuted V
// row loads. No LDS. XCD-affine causal-paired task map. Pinned K/V prefetch.
__global__ __launch_bounds__(768, 3) void attn_fwd(
    const u16* __restrict__ qg, const u16* __restrict__ kg,
    const u16* __restrict__ vtg, u16* __restrict__ og) {
  const int lane = threadIdx.x & 63;
  const int w = threadIdx.x >> 6;          // 0..11
  const int lrow = lane & 15, lkg = lane >> 4;

  // task map: each XCD (blockIdx&7) owns 3 heads; causal pairing for balance
  const int xcd = blockIdx.x & 7, sblk = blockIdx.x >> 3;
  const int pi = sblk * 6 + (w % 6);       // 0..191 per XCD
  const int bh = xcd * 3 + (pi >> 6);      // 0..23
  const int pq = pi & 63;
  const int qt = (w < 6) ? pq : (127 - pq);
  const int qbase = qt * 16;

  const u16* Q  = qg  + (size_t)bh * (2048 * 64);
  const u16* Kp = kg  + (size_t)bh * (2048 * 64);
  const u16* VT = vtg + (size_t)bh * (64 * 2048);

  short8 qf0 = *(const short8*)(Q + (qbase + lrow) * 64 + lkg * 8);
  short8 qf1 = *(const short8*)(Q + (qbase + lrow) * 64 + 32 + lkg * 8);

  const f32x4 z4 = {0.f, 0.f, 0.f, 0.f};
  f32x4 o[4] = {z4, z4, z4, z4};
  float m_ = -1e30f, l_ = 0.f;

  const int niter = (qbase + 16 + 63) >> 6;

  short8 kf[4][2];
  uint2 va[4][2], vb[4][2];
#pragma unroll
  for (int kb = 0; kb < 4; ++kb)
#pragma unroll
    for (int h = 0; h < 2; ++h)
      kf[kb][h] = *(const short8*)(Kp + (size_t)(kb * 16 + lrow) * 64 + h * 32 + lkg * 8);
#pragma unroll
  for (int db = 0; db < 4; ++db) {
    const u16* vrow = VT + (size_t)(db * 16 + lrow) * 2048;
#pragma unroll
    for (int h = 0; h < 2; ++h) {
      va[db][h] = *(const uint2*)(vrow + h * 32 + 4 * lkg);
      vb[db][h] = *(const uint2*)(vrow + h * 32 + 16 + 4 * lkg);
    }
  }

  const float c1 = 0.1803368801111244f;  // 0.125 * log2(e)
  const int q_abs = qbase + lrow;

  for (int it = 0; it < niter; ++it) {
    const int kv0 = it << 6;
    // ---- QK^T (swapped: rows = kv, cols = q) ----
    f32x4 s[4];
#pragma unroll
    for (int kb = 0; kb < 4; ++kb) {
      s[kb] = mfma_bf16(kf[kb][0], qf0, z4);
      s[kb] = mfma_bf16(kf[kb][1], qf1, s[kb]);
    }
    // ---- prefetch next K (in-place; pinned here) ----
    if (it + 1 < niter) {
      const u16* Kn = Kp + (size_t)(kv0 + 64) * 64;
#pragma unroll
      for (int kb = 0; kb < 4; ++kb)
#pragma unroll
        for (int h = 0; h < 2; ++h)
          kf[kb][h] = *(const short8*)(Kn + (size_t)(kb * 16 + lrow) * 64 + h * 32 + lkg * 8);
      __builtin_amdgcn_sched_barrier(0);
    }
    // ---- log2-domain scores + causal mask ----
#pragma unroll
    for (int kb = 0; kb < 4; ++kb)
#pragma unroll
      for (int i = 0; i < 4; ++i) s[kb][i] *= c1;
    if (kv0 + 64 > qbase) {
#pragma unroll
      for (int kb = 0; kb < 4; ++kb)
#pragma unroll
        for (int i = 0; i < 4; ++i)
          if (kv0 + kb * 16 + lkg * 4 + i > q_abs) s[kb][i] = -1e30f;
    }
    // ---- online softmax: 15 local max + 2 shfl ----
    f32x4 m03 = vmax4(vmax4(s[0], s[1]), vmax4(s[2], s[3]));
    float mt = fmaxf(fmaxf(m03[0], m03[1]), fmaxf(m03[2], m03[3]));
    mt = fmaxf(mt, __shfl_xor(mt, 16));
    mt = fmaxf(mt, __shfl_xor(mt, 32));
    float mn = fmaxf(m_, mt);
    float sclf = exp2v(m_ - mn);
    m_ = mn;
#pragma unroll
    for (int kb = 0; kb < 4; ++kb)
#pragma unroll
      for (int i = 0; i < 4; ++i) s[kb][i] = exp2v(s[kb][i] - mn);
    f32x4 st = (s[0] + s[1]) + (s[2] + s[3]);
    float rs = (st[0] + st[1]) + (st[2] + st[3]);
    rs += __shfl_xor(rs, 16);
    rs += __shfl_xor(rs, 32);
    l_ = l_ * sclf + rs;

    // ---- lane-local P pack (kv bijection: j0..3 -> 4*lkg+j, j4..7 -> 16+4*lkg+j) ----
    uint4 pa0u = { cvtpk(s[0][0], s[0][1]), cvtpk(s[0][2], s[0][3]),
                   cvtpk(s[1][0], s[1][1]), cvtpk(s[1][2], s[1][3]) };
    uint4 pa1u = { cvtpk(s[2][0], s[2][1]), cvtpk(s[2][2], s[2][3]),
                   cvtpk(s[3][0], s[3][1]), cvtpk(s[3][2], s[3][3]) };
    short8 pa0 = __builtin_bit_cast(short8, pa0u);
    short8 pa1 = __builtin_bit_cast(short8, pa1u);

    // ---- o rescale (broadcast scl per output q-row) ----
    float sc0 = __shfl(sclf, lkg * 4 + 0);
    float sc1 = __shfl(sclf, lkg * 4 + 1);
    float sc2 = __shfl(sclf, lkg * 4 + 2);
    float sc3 = __shfl(sclf, lkg * 4 + 3);
#pragma unroll
    for (int db = 0; db < 4; ++db) {
      o[db][0] *= sc0; o[db][1] *= sc1; o[db][2] *= sc2; o[db][3] *= sc3;
    }
    // ---- PV (V rows loaded in the same permuted order) ----
#pragma unroll
    for (int db = 0; db < 4; ++db) {
      uint4 u0 = {va[db][0].x, va[db][0].y, vb[db][0].x, vb[db][0].y};
      uint4 u1 = {va[db][1].x, va[db][1].y, vb[db][1].x, vb[db][1].y};
      o[db] = mfma_bf16(pa0, __builtin_bit_cast(short8, u0), o[db]);
      o[db] = mfma_bf16(pa1, __builtin_bit_cast(short8, u1), o[db]);
    }
    // ---- prefetch next V (pinned) ----
    if (it + 1 < niter) {
#pragma unroll
      for (int db = 0; db < 4; ++db) {
        const u16* vrow = VT + (size_t)(db * 16 + lrow) * 2048 + (kv0 + 64);
#pragma unroll
        for (int h = 0; h < 2; ++h) {
          va[db][h] = *(const uint2*)(vrow + h * 32 + 4 * lkg);
          vb[db][h] = *(const uint2*)(vrow + h * 32 + 16 + 4 * lkg);
        }
      }
      __builtin_amdgcn_sched_barrier(0);
    }
  }

  // ---- epilogue ----
  int b = bh / 12, h = bh - b * 12;
  float nn[4];
  nn[0] = 1.0f / __shfl(l_, lkg * 4 + 0);
  nn[1] = 1.0f / __shfl(l_, lkg * 4 + 1);
  nn[2] = 1.0f / __shfl(l_, lkg * 4 + 2);
  nn[3] = 1.0f / __shfl(l_, lkg * 4 + 3);
#pragma unroll
  for (int i = 0; i < 4; ++i) {
    int qr = qbase + lkg * 4 + i;
    u16* orow = og + ((size_t)(b * 2048 + qr)) * 768 + h * 64 + lrow;
    orow[0]  = f2bf(o[0][i] * nn[i]);
    orow[16] = f2bf(o[1][i] * nn[i]);
    orow[32] = f2bf(o[2][i] * nn[i]);
    orow[48] = f2bf(o[3][i] * nn[i]);
  }
}

// ---------- launch ----------
extern "C" void kernel_launch(void* const* d_in, const int* in_sizes, int n_in,
                              void* d_out, int out_size, void* d_ws, size_t ws_size,
                              hipStream_t stream) {
  const float* hs = (const float*)d_in[0];
  const float* wq = (const float*)d_in[1];
  const float* wk = (const float*)d_in[2];
  const float* wv = (const float*)d_in[3];
  const float* wo = (const float*)d_in[4];
  // d_in[5] (attn_mask) is exactly causal -1e9: implemented in-kernel.
  float* out = (float*)d_out;
  char* ws = (char*)d_ws;

  u16* hbf = (u16*)(ws);               // 4096x768 bf16          (6291456 B)
  u16* wbf = (u16*)(ws + 6291456);     // wq|wk|wv|wo bf16       (4718592 B)
  u16* qb  = (u16*)(ws + 11010048);    // [B,H,S,64] bf16        (6291456 B)
  u16* kb  = (u16*)(ws + 17301504);    // [B,H,S,64] bf16        (6291456 B)
  u16* vtb = (u16*)(ws + 23592960);    // [B,H,64,S] bf16        (6291456 B)
  u16* ob  = (u16*)(ws + 29884416);    // [B,S,768]  bf16        (6291456 B)

  cvt_kernel<<<dim3(3072, 5), 256, 0, stream>>>(hs, wq, wk, wv, wo, hbf, wbf);
  gemm_bt<0><<<dim3(32, 18), 256, 0, stream>>>(hbf, wbf, qb, kb, vtb, nullptr);
  rope_kernel<<<dim3(6144, 2), 256, 0, stream>>>(qb, kb);
  attn_fwd<<<dim3(256), 768, 0, stream>>>(qb, kb, vtb, ob);
  gemm_bt<1><<<dim3(32, 6), 256, 0, stream>>>(ob, wbf + 1769472, nullptr, nullptr, nullptr, out);
}

// Round 4
// 125.546 us; speedup vs baseline: 1.6654x; 1.6654x over previous
//
#include <hip/hip_runtime.h>

typedef unsigned short u16;
typedef short short8 __attribute__((ext_vector_type(8)));
typedef float f32x4 __attribute__((ext_vector_type(4)));

static_assert(sizeof(short8) == 16, "short8 must be 16B");

// ---------- helpers ----------
__device__ __forceinline__ u16 f2bf(float f) {
  unsigned u = __float_as_uint(f);
  u += 0x7FFFu + ((u >> 16) & 1u);   // RNE
  return (u16)(u >> 16);
}
__device__ __forceinline__ float bf2f(u16 h) { return __uint_as_float(((unsigned)h) << 16); }

__device__ __forceinline__ f32x4 mfma_bf16(short8 a, short8 b, f32x4 c) {
  return __builtin_amdgcn_mfma_f32_16x16x32_bf16(a, b, c, 0, 0, 0);
}

__device__ __forceinline__ void gload_lds16(const void* g, void* l) {
  __builtin_amdgcn_global_load_lds((__attribute__((address_space(1))) void*)g,
                                   (__attribute__((address_space(3))) void*)l, 16, 0, 0);
}

__device__ __forceinline__ float exp2v(float x) {
  float r; asm("v_exp_f32 %0, %1" : "=v"(r) : "v"(x)); return r;
}
__device__ __forceinline__ unsigned cvtpk(float lo, float hi) {
  unsigned r; asm("v_cvt_pk_bf16_f32 %0, %1, %2" : "=v"(r) : "v"(lo), "v"(hi)); return r;
}
__device__ __forceinline__ f32x4 vmax4(f32x4 a, f32x4 b) {
  f32x4 r;
  r[0] = fmaxf(a[0], b[0]); r[1] = fmaxf(a[1], b[1]);
  r[2] = fmaxf(a[2], b[2]); r[3] = fmaxf(a[3], b[3]);
  return r;
}

// ---------- fp32 -> bf16 conversion (hidden + 4 weights) ----------
__global__ __launch_bounds__(256) void cvt_kernel(
    const float* __restrict__ hs, const float* __restrict__ wq, const float* __restrict__ wk,
    const float* __restrict__ wv, const float* __restrict__ wo,
    u16* __restrict__ hbf, u16* __restrict__ wbf) {
  const float* src; u16* dst; int n4;
  switch (blockIdx.y) {
    case 0:  src = hs; dst = hbf;            n4 = 786432; break;  // 4096*768/4
    case 1:  src = wq; dst = wbf;            n4 = 147456; break;  // 768*768/4
    case 2:  src = wk; dst = wbf + 589824;   n4 = 147456; break;
    case 3:  src = wv; dst = wbf + 1179648;  n4 = 147456; break;
    default: src = wo; dst = wbf + 1769472;  n4 = 147456; break;
  }
  int i = blockIdx.x * 256 + threadIdx.x;
  if (i >= n4) return;
  float4 v = ((const float4*)src)[i];
  uint2 r;
  r.x = (unsigned)f2bf(v.x) | ((unsigned)f2bf(v.y) << 16);
  r.y = (unsigned)f2bf(v.z) | ((unsigned)f2bf(v.w) << 16);
  ((uint2*)dst)[i] = r;
}

// ---------- RoPE, in-place on q and k ([B*H, S, 64] bf16) ----------
__global__ __launch_bounds__(256) void rope_kernel(u16* __restrict__ qb, u16* __restrict__ kb) {
  int idx = blockIdx.x * 256 + threadIdx.x;   // < 24*2048*32 = 1572864
  u16* buf = blockIdx.y ? kb : qb;
  int j = idx & 31;
  int sbh = idx >> 5;                         // bh*2048 + s
  int s = sbh & 2047;
  size_t base = (size_t)sbh * 64;
  float x1 = bf2f(buf[base + j]);
  float x2 = bf2f(buf[base + 32 + j]);
  float freq = __expf(-0.2878231366242557f * (float)j);  // 10000^(-j/32)
  float th = (float)s * freq;
  float sn, cs;
  __sincosf(th, &sn, &cs);
  buf[base + j]      = f2bf(x1 * cs - x2 * sn);
  buf[base + 32 + j] = f2bf(x2 * cs + x1 * sn);
}

// ---------- GEMM: C(MxN) = A(MxK) * B(NxK)^T, bf16 in, m97-style ----------
// MODE 0: QKV epilogue -> q[B,H,S,D], k[B,H,S,D], vt[B,H,D,S] (bf16)
// MODE 1: fp32 epilogue -> fout row-major (M x 768)
template <int MODE>
__global__ __launch_bounds__(256) void gemm_bt(
    const u16* __restrict__ A, const u16* __restrict__ Bm,
    u16* __restrict__ qb, u16* __restrict__ kb, u16* __restrict__ vtb,
    float* __restrict__ fout) {
  __shared__ char sA[16384];   // 128 rows x 64 bf16 (8 x 16B slots, XOR-swizzled)
  __shared__ char sB[16384];
  const int K = 768;
  const int t = threadIdx.x;
  const int lane = t & 63;
  const int w = t >> 6;              // wave 0..3
  const int wr = w >> 1, wc = w & 1; // 2x2 wave grid of 64x64 subtiles
  const int lrow = lane & 15, lkg = lane >> 4;
  const int arow0 = blockIdx.x * 128, brow0 = blockIdx.y * 128;

  f32x4 acc[4][4];
  const f32x4 z4 = {0.f, 0.f, 0.f, 0.f};
#pragma unroll
  for (int m = 0; m < 4; ++m)
#pragma unroll
    for (int n = 0; n < 4; ++n) acc[m][n] = z4;

  const int srow = t >> 3;   // 0..31 (staging row within 32-row chunk)
  const int sslot = t & 7;   // physical 16B slot

  for (int kt = 0; kt < K; kt += 64) {
    __syncthreads();
#pragma unroll
    for (int it = 0; it < 4; ++it) {
      int r = it * 32 + srow;
      int ls = sslot ^ (r & 7);   // inverse-swizzled global source slot
      gload_lds16(A + (size_t)(arow0 + r) * K + (kt + ls * 8), sA + it * 4096 + w * 1024);
      gload_lds16(Bm + (size_t)(brow0 + r) * K + (kt + ls * 8), sB + it * 4096 + w * 1024);
    }
    __syncthreads();
#pragma unroll
    for (int kk = 0; kk < 2; ++kk) {
      short8 af[4], bfr[4];
#pragma unroll
      for (int m = 0; m < 4; ++m) {
        int row = wr * 64 + m * 16 + lrow;
        int ph = (kk * 4 + lkg) ^ (row & 7);
        af[m] = *(const short8*)(sA + row * 128 + ph * 16);
      }
#pragma unroll
      for (int n = 0; n < 4; ++n) {
        int row = wc * 64 + n * 16 + lrow;
        int ph = (kk * 4 + lkg) ^ (row & 7);
        bfr[n] = *(const short8*)(sB + row * 128 + ph * 16);
      }
#pragma unroll
      for (int m = 0; m < 4; ++m)
#pragma unroll
        for (int n = 0; n < 4; ++n) acc[m][n] = mfma_bf16(af[m], bfr[n], acc[m][n]);
    }
  }

#pragma unroll
  for (int m = 0; m < 4; ++m) {
#pragma unroll
    for (int n = 0; n < 4; ++n) {
#pragma unroll
      for (int i = 0; i < 4; ++i) {
        int row = arow0 + wr * 64 + m * 16 + (lane >> 4) * 4 + i;
        int col = brow0 + wc * 64 + n * 16 + (lane & 15);
        float v = acc[m][n][i];
        if (MODE == 1) {
          fout[(size_t)row * 768 + col] = v;
        } else {
          int b = row >> 11, s = row & 2047;
          int qsel = col / 768;            // uniform per block (768 % 128 == 0)
          int oc = col - qsel * 768;
          int h = oc >> 6, d = oc & 63;
          size_t bh = (size_t)(b * 12 + h);
          u16 bv = f2bf(v);
          if (qsel == 0)      qb[(bh * 2048 + s) * 64 + d] = bv;
          else if (qsel == 1) kb[(bh * 2048 + s) * 64 + d] = bv;
          else                vtb[(bh * 64 + d) * 2048 + s] = bv;  // V transposed
        }
      }
    }
  }
}

// ---------- causal flash attention v4 ----------
// Block = (head, 128 q-rows), 4 waves x 32 q-rows. K/V tiles (KVBLK=64) shared
// via LDS, double-buffered, staged with async global_load_lds (XOR-swizzled:
// pre-swizzled global source + swizzled ds_read). 2-phase stage/compute/barrier.
// Swapped QK^T, in-register softmax, lane-local P pack (r3-verified algebra).
__global__ __launch_bounds__(256, 2) void attn_fwd(
    const u16* __restrict__ qg, const u16* __restrict__ kg,
    const u16* __restrict__ vtg, u16* __restrict__ og) {
  __shared__ __align__(16) char sm[32768];   // [2 bufs][ K 8KB | V 8KB ]
  const int lane = threadIdx.x & 63;
  const int w = threadIdx.x >> 6;            // 0..3
  const int lrow = lane & 15, lkg = lane >> 4;

  const int u = blockIdx.x;                  // 0..383
  const int bh = u % 24;
  const int qc = 15 - (u / 24);              // big blocks dispatched first
  const int qw = qc * 128 + w * 32;          // wave's first q-row
  const int niter = 2 * qc + 2;              // kv tiles of 64 up to (qc+1)*128

  const u16* Q  = qg  + (size_t)bh * (2048 * 64);
  const u16* Kp = kg  + (size_t)bh * (2048 * 64);
  const u16* VT = vtg + (size_t)bh * (64 * 2048);

  // Q fragments: qset qs covers q-rows qw+qs*16 .. +16
  short8 qf[2][2];
#pragma unroll
  for (int qs = 0; qs < 2; ++qs)
#pragma unroll
    for (int h = 0; h < 2; ++h)
      qf[qs][h] = *(const short8*)(Q + (size_t)(qw + qs * 16 + lrow) * 64 + h * 32 + lkg * 8);

  const f32x4 z4 = {0.f, 0.f, 0.f, 0.f};
  f32x4 o[2][4] = {{z4, z4, z4, z4}, {z4, z4, z4, z4}};
  float m_[2] = {-1e30f, -1e30f}, l_[2] = {0.f, 0.f};

  // staging: wave w stages K rows [w*16, +16) and VT rows [w*16, +16)
  const int s_rl = lane >> 3;                // 0..7
  const int s_p  = lane & 7;                 // 16B slot
  auto STAGE = [&](int t, int b) {
    const int kv0 = t << 6;
    char* sk = sm + b * 16384;
    char* sv = sk + 8192;
    int r0 = w * 16 + s_rl, r1 = r0 + 8;
    gload_lds16(Kp + (size_t)(kv0 + r0) * 64 + ((s_p ^ (r0 & 7)) << 3), sk + w * 2048);
    gload_lds16(Kp + (size_t)(kv0 + r1) * 64 + ((s_p ^ (r1 & 7)) << 3), sk + w * 2048 + 1024);
    gload_lds16(VT + (size_t)r0 * 2048 + kv0 + ((s_p ^ (r0 & 7)) << 3), sv + w * 2048);
    gload_lds16(VT + (size_t)r1 * 2048 + kv0 + ((s_p ^ (r1 & 7)) << 3), sv + w * 2048 + 1024);
  };

  STAGE(0, 0);
  __syncthreads();

  const float c1 = 0.1803368801111244f;  // 0.125 * log2(e)

  for (int t = 0; t < niter; ++t) {
    const int kv0 = t << 6;
    const int cur = t & 1;
    if (t + 1 < niter) STAGE(t + 1, cur ^ 1);   // async; drains at the barrier

    if (kv0 < qw + 32) {                        // wave has unmasked work here
      const char* sk = sm + cur * 16384;
      const char* sv = sk + 8192;

      // ---- QK^T (swapped: A=K rows=kv, B=Q cols=q) ----
      f32x4 s[2][4];
#pragma unroll
      for (int kb = 0; kb < 4; ++kb) {
        int r = kb * 16 + lrow, sw = r & 7;
        short8 kf0 = *(const short8*)(sk + r * 128 + ((lkg ^ sw) << 4));
        short8 kf1 = *(const short8*)(sk + r * 128 + (((4 + lkg) ^ sw) << 4));
        s[0][kb] = mfma_bf16(kf0, qf[0][0], z4);
        s[0][kb] = mfma_bf16(kf1, qf[0][1], s[0][kb]);
        s[1][kb] = mfma_bf16(kf0, qf[1][0], z4);
        s[1][kb] = mfma_bf16(kf1, qf[1][1], s[1][kb]);
      }

      // ---- online softmax per qset (log2 domain) ----
      short8 pa[2][2];
#pragma unroll
      for (int qs = 0; qs < 2; ++qs) {
#pragma unroll
        for (int kb = 0; kb < 4; ++kb)
#pragma unroll
          for (int i = 0; i < 4; ++i) s[qs][kb][i] *= c1;
        if (kv0 + 63 > qw) {
          int qa = qw + qs * 16 + lrow;
#pragma unroll
          for (int kb = 0; kb < 4; ++kb)
#pragma unroll
            for (int i = 0; i < 4; ++i)
              if (kv0 + kb * 16 + lkg * 4 + i > qa) s[qs][kb][i] = -1e30f;
        }
        f32x4 m03 = vmax4(vmax4(s[qs][0], s[qs][1]), vmax4(s[qs][2], s[qs][3]));
        float mt = fmaxf(fmaxf(m03[0], m03[1]), fmaxf(m03[2], m03[3]));
        mt = fmaxf(mt, __shfl_xor(mt, 16));
        mt = fmaxf(mt, __shfl_xor(mt, 32));
        float mn = fmaxf(m_[qs], mt);
        float sclf = exp2v(m_[qs] - mn);
        m_[qs] = mn;
#pragma unroll
        for (int kb = 0; kb < 4; ++kb)
#pragma unroll
          for (int i = 0; i < 4; ++i) s[qs][kb][i] = exp2v(s[qs][kb][i] - mn);
        f32x4 st = (s[qs][0] + s[qs][1]) + (s[qs][2] + s[qs][3]);
        float rs = (st[0] + st[1]) + (st[2] + st[3]);
        rs += __shfl_xor(rs, 16);
        rs += __shfl_xor(rs, 32);
        l_[qs] = l_[qs] * sclf + rs;

        // lane-local P pack (kv bijection j0..3 -> 4lkg+i, j4..7 -> 16+4lkg+i)
        uint4 p0 = { cvtpk(s[qs][0][0], s[qs][0][1]), cvtpk(s[qs][0][2], s[qs][0][3]),
                     cvtpk(s[qs][1][0], s[qs][1][1]), cvtpk(s[qs][1][2], s[qs][1][3]) };
        uint4 p1 = { cvtpk(s[qs][2][0], s[qs][2][1]), cvtpk(s[qs][2][2], s[qs][2][3]),
                     cvtpk(s[qs][3][0], s[qs][3][1]), cvtpk(s[qs][3][2], s[qs][3][3]) };
        pa[qs][0] = __builtin_bit_cast(short8, p0);
        pa[qs][1] = __builtin_bit_cast(short8, p1);

        // o rescale (broadcast scl per output q-row)
        float sc0 = __shfl(sclf, lkg * 4 + 0);
        float sc1 = __shfl(sclf, lkg * 4 + 1);
        float sc2 = __shfl(sclf, lkg * 4 + 2);
        float sc3 = __shfl(sclf, lkg * 4 + 3);
#pragma unroll
        for (int db = 0; db < 4; ++db) {
          o[qs][db][0] *= sc0; o[qs][db][1] *= sc1;
          o[qs][db][2] *= sc2; o[qs][db][3] *= sc3;
        }
      }

      // ---- PV: V fragments from LDS (permuted kv order matching pa) ----
#pragma unroll
      for (int db = 0; db < 4; ++db) {
        int d = db * 16 + lrow, sw = d & 7;
#pragma unroll
        for (int hk = 0; hk < 2; ++hk) {
          int b1 = 64 * hk + 8 * lkg;   // byte offset of kv {hk*32+4lkg ..+4}
          int b2 = b1 + 32;             // kv {hk*32+16+4lkg ..+4}
          uint2 va = *(const uint2*)(sv + d * 128 + ((((b1 >> 4) ^ sw) << 4) | (b1 & 15)));
          uint2 vb = *(const uint2*)(sv + d * 128 + ((((b2 >> 4) ^ sw) << 4) | (b2 & 15)));
          uint4 uu = {va.x, va.y, vb.x, vb.y};
          short8 vf = __builtin_bit_cast(short8, uu);
          o[0][db] = mfma_bf16(pa[0][hk], vf, o[0][db]);
          o[1][db] = mfma_bf16(pa[1][hk], vf, o[1][db]);
        }
      }
    }
    __syncthreads();   // staging of t+1 drained; all reads of buf[cur] done
  }

  // ---- epilogue ----
  int b = bh / 12, h = bh - b * 12;
#pragma unroll
  for (int qs = 0; qs < 2; ++qs) {
    float nn[4];
    nn[0] = 1.0f / __shfl(l_[qs], lkg * 4 + 0);
    nn[1] = 1.0f / __shfl(l_[qs], lkg * 4 + 1);
    nn[2] = 1.0f / __shfl(l_[qs], lkg * 4 + 2);
    nn[3] = 1.0f / __shfl(l_[qs], lkg * 4 + 3);
#pragma unroll
    for (int i = 0; i < 4; ++i) {
      int qr = qw + qs * 16 + lkg * 4 + i;
      u16* orow = og + ((size_t)(b * 2048 + qr)) * 768 + h * 64 + lrow;
      orow[0]  = f2bf(o[qs][0][i] * nn[i]);
      orow[16] = f2bf(o[qs][1][i] * nn[i]);
      orow[32] = f2bf(o[qs][2][i] * nn[i]);
      orow[48] = f2bf(o[qs][3][i] * nn[i]);
    }
  }
}

// ---------- launch ----------
extern "C" void kernel_launch(void* const* d_in, const int* in_sizes, int n_in,
                              void* d_out, int out_size, void* d_ws, size_t ws_size,
                              hipStream_t stream) {
  const float* hs = (const float*)d_in[0];
  const float* wq = (const float*)d_in[1];
  const float* wk = (const float*)d_in[2];
  const float* wv = (const float*)d_in[3];
  const float* wo = (const float*)d_in[4];
  // d_in[5] (attn_mask) is exactly causal -1e9: implemented in-kernel.
  float* out = (float*)d_out;
  char* ws = (char*)d_ws;

  u16* hbf = (u16*)(ws);               // 4096x768 bf16          (6291456 B)
  u16* wbf = (u16*)(ws + 6291456);     // wq|wk|wv|wo bf16       (4718592 B)
  u16* qb  = (u16*)(ws + 11010048);    // [B,H,S,64] bf16        (6291456 B)
  u16* kb  = (u16*)(ws + 17301504);    // [B,H,S,64] bf16        (6291456 B)
  u16* vtb = (u16*)(ws + 23592960);    // [B,H,64,S] bf16        (6291456 B)
  u16* ob  = (u16*)(ws + 29884416);    // [B,S,768]  bf16        (6291456 B)

  cvt_kernel<<<dim3(3072, 5), 256, 0, stream>>>(hs, wq, wk, wv, wo, hbf, wbf);
  gemm_bt<0><<<dim3(32, 18), 256, 0, stream>>>(hbf, wbf, qb, kb, vtb, nullptr);
  rope_kernel<<<dim3(6144, 2), 256, 0, stream>>>(qb, kb);
  attn_fwd<<<dim3(384), 256, 0, stream>>>(qb, kb, vtb, ob);
  gemm_bt<1><<<dim3(32, 6), 256, 0, stream>>>(ob, wbf + 1769472, nullptr, nullptr, nullptr, out);
}

// Round 5
// 96.194 us; speedup vs baseline: 2.1736x; 1.3051x over previous
//
#include <hip/hip_runtime.h>

typedef unsigned short u16;
typedef short short8 __attribute__((ext_vector_type(8)));
typedef float f32x4 __attribute__((ext_vector_type(4)));

static_assert(sizeof(short8) == 16, "short8 must be 16B");

// ---------- helpers ----------
__device__ __forceinline__ u16 f2bf(float f) {
  unsigned u = __float_as_uint(f);
  u += 0x7FFFu + ((u >> 16) & 1u);   // RNE
  return (u16)(u >> 16);
}
__device__ __forceinline__ float bf2f(u16 h) { return __uint_as_float(((unsigned)h) << 16); }

__device__ __forceinline__ f32x4 mfma_bf16(short8 a, short8 b, f32x4 c) {
  return __builtin_amdgcn_mfma_f32_16x16x32_bf16(a, b, c, 0, 0, 0);
}

__device__ __forceinline__ void gload_lds16(const void* g, void* l) {
  __builtin_amdgcn_global_load_lds((__attribute__((address_space(1))) void*)g,
                                   (__attribute__((address_space(3))) void*)l, 16, 0, 0);
}

__device__ __forceinline__ float exp2v(float x) {
  float r; asm("v_exp_f32 %0, %1" : "=v"(r) : "v"(x)); return r;
}
__device__ __forceinline__ unsigned cvtpk(float lo, float hi) {
  unsigned r; asm("v_cvt_pk_bf16_f32 %0, %1, %2" : "=v"(r) : "v"(lo), "v"(hi)); return r;
}
__device__ __forceinline__ f32x4 vmax4(f32x4 a, f32x4 b) {
  f32x4 r;
  r[0] = fmaxf(a[0], b[0]); r[1] = fmaxf(a[1], b[1]);
  r[2] = fmaxf(a[2], b[2]); r[3] = fmaxf(a[3], b[3]);
  return r;
}

// ---------- fp32 -> bf16 conversion (hidden + 4 weights) ----------
__global__ __launch_bounds__(256) void cvt_kernel(
    const float* __restrict__ hs, const float* __restrict__ wq, const float* __restrict__ wk,
    const float* __restrict__ wv, const float* __restrict__ wo,
    u16* __restrict__ hbf, u16* __restrict__ wbf) {
  const float* src; u16* dst; int n4;
  switch (blockIdx.y) {
    case 0:  src = hs; dst = hbf;            n4 = 786432; break;  // 4096*768/4
    case 1:  src = wq; dst = wbf;            n4 = 147456; break;  // 768*768/4
    case 2:  src = wk; dst = wbf + 589824;   n4 = 147456; break;
    case 3:  src = wv; dst = wbf + 1179648;  n4 = 147456; break;
    default: src = wo; dst = wbf + 1769472;  n4 = 147456; break;
  }
  int i = blockIdx.x * 256 + threadIdx.x;
  if (i >= n4) return;
  float4 v = ((const float4*)src)[i];
  uint2 r;
  r.x = (unsigned)f2bf(v.x) | ((unsigned)f2bf(v.y) << 16);
  r.y = (unsigned)f2bf(v.z) | ((unsigned)f2bf(v.w) << 16);
  ((uint2*)dst)[i] = r;
}

// ---------- GEMM: C(MxN) = A(MxK) * B(NxK)^T, bf16 in, m97-style ----------
// MODE 0: QKV epilogue with fused RoPE (q,k) + q pre-scale by 0.125*log2e;
//         q,k -> [B,H,S,64], v -> transposed [B,H,64,S] (bf16)
// MODE 1: fp32 epilogue -> fout row-major (M x 768)
template <int MODE>
__global__ __launch_bounds__(256) void gemm_bt(
    const u16* __restrict__ A, const u16* __restrict__ Bm,
    u16* __restrict__ qb, u16* __restrict__ kb, u16* __restrict__ vtb,
    float* __restrict__ fout) {
  __shared__ char sA[16384];   // 128 rows x 64 bf16 (8 x 16B slots, XOR-swizzled)
  __shared__ char sB[16384];
  const int K = 768;
  const int t = threadIdx.x;
  const int lane = t & 63;
  const int w = t >> 6;              // wave 0..3
  const int wr = w >> 1, wc = w & 1; // 2x2 wave grid of 64x64 subtiles
  const int lrow = lane & 15, lkg = lane >> 4;
  const int arow0 = blockIdx.x * 128, brow0 = blockIdx.y * 128;

  f32x4 acc[4][4];
  const f32x4 z4 = {0.f, 0.f, 0.f, 0.f};
#pragma unroll
  for (int m = 0; m < 4; ++m)
#pragma unroll
    for (int n = 0; n < 4; ++n) acc[m][n] = z4;

  const int srow = t >> 3;   // 0..31 (staging row within 32-row chunk)
  const int sslot = t & 7;   // physical 16B slot

  for (int kt = 0; kt < K; kt += 64) {
    __syncthreads();
#pragma unroll
    for (int it = 0; it < 4; ++it) {
      int r = it * 32 + srow;
      int ls = sslot ^ (r & 7);   // inverse-swizzled global source slot
      gload_lds16(A + (size_t)(arow0 + r) * K + (kt + ls * 8), sA + it * 4096 + w * 1024);
      gload_lds16(Bm + (size_t)(brow0 + r) * K + (kt + ls * 8), sB + it * 4096 + w * 1024);
    }
    __syncthreads();
#pragma unroll
    for (int kk = 0; kk < 2; ++kk) {
      short8 af[4], bfr[4];
#pragma unroll
      for (int m = 0; m < 4; ++m) {
        int row = wr * 64 + m * 16 + lrow;
        int ph = (kk * 4 + lkg) ^ (row & 7);
        af[m] = *(const short8*)(sA + row * 128 + ph * 16);
      }
#pragma unroll
      for (int n = 0; n < 4; ++n) {
        int row = wc * 64 + n * 16 + lrow;
        int ph = (kk * 4 + lkg) ^ (row & 7);
        bfr[n] = *(const short8*)(sB + row * 128 + ph * 16);
      }
#pragma unroll
      for (int m = 0; m < 4; ++m)
#pragma unroll
        for (int n = 0; n < 4; ++n) acc[m][n] = mfma_bf16(af[m], bfr[n], acc[m][n]);
    }
  }

  if (MODE == 1) {
#pragma unroll
    for (int m = 0; m < 4; ++m)
#pragma unroll
      for (int n = 0; n < 4; ++n)
#pragma unroll
        for (int i = 0; i < 4; ++i) {
          int row = arow0 + wr * 64 + m * 16 + lkg * 4 + i;
          int col = brow0 + wc * 64 + n * 16 + lrow;
          fout[(size_t)row * 768 + col] = acc[m][n][i];
        }
  } else {
    const int qsel = brow0 / 768;    // 0=q 1=k 2=v, uniform per block
    if (qsel < 2) {
      // fused RoPE: pairs (d, d+32) = (acc[m][n2], acc[m][n2+2]), d = n2*16+lrow
      u16* dst = qsel ? kb : qb;
      const float oscale = qsel ? 1.0f : 0.1803368801111244f;  // 0.125*log2(e) into q
      float fr[2];
      fr[0] = __expf(-0.2878231366242557f * (float)lrow);         // 10000^(-d/32)
      fr[1] = __expf(-0.2878231366242557f * (float)(16 + lrow));
      const int hh = ((brow0 - qsel * 768) >> 6) + wc;            // head index
#pragma unroll
      for (int m = 0; m < 4; ++m)
#pragma unroll
        for (int i = 0; i < 4; ++i) {
          int row = arow0 + wr * 64 + m * 16 + lkg * 4 + i;
          int b = row >> 11, s = row & 2047;
          size_t base = ((size_t)(b * 12 + hh) * 2048 + s) * 64;
#pragma unroll
          for (int n2 = 0; n2 < 2; ++n2) {
            float x1 = acc[m][n2][i], x2 = acc[m][n2 + 2][i];
            float th = (float)s * fr[n2];
            float sn, cs;
            __sincosf(th, &sn, &cs);
            dst[base + n2 * 16 + lrow]      = f2bf((x1 * cs - x2 * sn) * oscale);
            dst[base + 32 + n2 * 16 + lrow] = f2bf((x2 * cs + x1 * sn) * oscale);
          }
        }
    } else {
#pragma unroll
      for (int m = 0; m < 4; ++m)
#pragma unroll
        for (int n = 0; n < 4; ++n)
#pragma unroll
          for (int i = 0; i < 4; ++i) {
            int row = arow0 + wr * 64 + m * 16 + lkg * 4 + i;
            int col = brow0 + wc * 64 + n * 16 + lrow;
            int b = row >> 11, s = row & 2047;
            int oc = col - 1536, h = oc >> 6, d = oc & 63;
            vtb[((size_t)(b * 12 + h) * 64 + d) * 2048 + s] = f2bf(acc[m][n][i]);
          }
    }
  }
}

// ---------- causal flash attention v5 ----------
// 768 blocks = (head, 64 q-rows), 4 waves x 16 q-rows; niter = qc+1 uniform.
// K/V KVBLK=64 shared via LDS (async global_load_lds, XOR-swizzled), dbuf,
// one barrier/iter. Swapped QK^T, in-register softmax, defer-max (THR=8 log2),
// lane-partial l (epilogue reduce). Q pre-scaled by 0.125*log2e in GEMM.
__global__ __launch_bounds__(256, 4) void attn_fwd(
    const u16* __restrict__ qg, const u16* __restrict__ kg,
    const u16* __restrict__ vtg, u16* __restrict__ og) {
  __shared__ __align__(16) char sm[32768];   // [2 bufs][ K 8KB | V 8KB ]
  const int lane = threadIdx.x & 63;
  const int w = threadIdx.x >> 6;            // 0..3
  const int lrow = lane & 15, lkg = lane >> 4;

  const int u = blockIdx.x;                  // 0..767
  const int xcd = u & 7, vv = u >> 3;        // heads pinned to XCDs; big-first
  const int bh = xcd * 3 + (vv % 3);
  const int qc = 31 - (vv / 3);              // 64-row q-chunk, qc=31 dispatched first
  const int qw = qc * 64 + w * 16;           // wave's first q-row
  const int niter = qc + 1;

  const u16* Q  = qg  + (size_t)bh * (2048 * 64);
  const u16* Kp = kg  + (size_t)bh * (2048 * 64);
  const u16* VT = vtg + (size_t)bh * (64 * 2048);

  short8 qf[2];
#pragma unroll
  for (int h = 0; h < 2; ++h)
    qf[h] = *(const short8*)(Q + (size_t)(qw + lrow) * 64 + h * 32 + lkg * 8);

  const f32x4 z4 = {0.f, 0.f, 0.f, 0.f};
  f32x4 o[4] = {z4, z4, z4, z4};
  float m_ = -1e30f, l_ = 0.f;

  // staging: wave w stages K rows [w*16,+16) and VT rows [w*16,+16)
  const int s_rl = lane >> 3;                // 0..7
  const int s_p  = lane & 7;                 // physical 16B slot
  auto STAGE = [&](int t, int b) {
    const int kv0 = t << 6;
    char* sk = sm + b * 16384;
    char* sv = sk + 8192;
    int r0 = w * 16 + s_rl, r1 = r0 + 8;
    gload_lds16(Kp + (size_t)(kv0 + r0) * 64 + ((s_p ^ (r0 & 7)) << 3), sk + w * 2048);
    gload_lds16(Kp + (size_t)(kv0 + r1) * 64 + ((s_p ^ (r1 & 7)) << 3), sk + w * 2048 + 1024);
    gload_lds16(VT + (size_t)r0 * 2048 + kv0 + ((s_p ^ (r0 & 7)) << 3), sv + w * 2048);
    gload_lds16(VT + (size_t)r1 * 2048 + kv0 + ((s_p ^ (r1 & 7)) << 3), sv + w * 2048 + 1024);
  };

  STAGE(0, 0);
  __syncthreads();

  for (int t = 0; t < niter; ++t) {
    const int kv0 = t << 6;
    const int cur = t & 1;
    if (t + 1 < niter) STAGE(t + 1, cur ^ 1);   // async; drains at the barrier

    const char* sk = sm + cur * 16384;
    const char* sv = sk + 8192;

    // ---- QK^T (swapped: A=K rows=kv, B=Q cols=q); scores already log2-scaled ----
    f32x4 s[4];
#pragma unroll
    for (int kb = 0; kb < 4; ++kb) {
      int r = kb * 16 + lrow, sw = r & 7;
      short8 kf0 = *(const short8*)(sk + r * 128 + ((lkg ^ sw) << 4));
      short8 kf1 = *(const short8*)(sk + r * 128 + (((4 + lkg) ^ sw) << 4));
      s[kb] = mfma_bf16(kf0, qf[0], z4);
      s[kb] = mfma_bf16(kf1, qf[1], s[kb]);
    }

    // ---- causal mask (only the diagonal tile) ----
    if (t == qc) {
      int qa = qw + lrow;
#pragma unroll
      for (int kb = 0; kb < 4; ++kb)
#pragma unroll
        for (int i = 0; i < 4; ++i)
          if (kv0 + kb * 16 + lkg * 4 + i > qa) s[kb][i] = -1e30f;
    }

    // ---- online softmax with defer-max ----
    f32x4 m03 = vmax4(vmax4(s[0], s[1]), vmax4(s[2], s[3]));
    float mt = fmaxf(fmaxf(m03[0], m03[1]), fmaxf(m03[2], m03[3]));
    mt = fmaxf(mt, __shfl_xor(mt, 16));
    mt = fmaxf(mt, __shfl_xor(mt, 32));
    if (__any(mt > m_ + 8.0f)) {               // rare rescale path
      float mn = fmaxf(m_, mt);
      float sclf = exp2v(m_ - mn);
      m_ = mn;
      l_ *= sclf;                              // l_ is per-lane (q = lrow): local
      float sc0 = __shfl(sclf, lkg * 4 + 0);
      float sc1 = __shfl(sclf, lkg * 4 + 1);
      float sc2 = __shfl(sclf, lkg * 4 + 2);
      float sc3 = __shfl(sclf, lkg * 4 + 3);
#pragma unroll
      for (int db = 0; db < 4; ++db) {
        o[db][0] *= sc0; o[db][1] *= sc1; o[db][2] *= sc2; o[db][3] *= sc3;
      }
    }
#pragma unroll
    for (int kb = 0; kb < 4; ++kb)
#pragma unroll
      for (int i = 0; i < 4; ++i) s[kb][i] = exp2v(s[kb][i] - m_);
    f32x4 st = (s[0] + s[1]) + (s[2] + s[3]);
    l_ += (st[0] + st[1]) + (st[2] + st[3]);   // partial over this lane's kv slots

    // ---- lane-local P pack (kv bijection j0..3 -> 4lkg+i, j4..7 -> 16+4lkg+i) ----
    uint4 p0 = { cvtpk(s[0][0], s[0][1]), cvtpk(s[0][2], s[0][3]),
                 cvtpk(s[1][0], s[1][1]), cvtpk(s[1][2], s[1][3]) };
    uint4 p1 = { cvtpk(s[2][0], s[2][1]), cvtpk(s[2][2], s[2][3]),
                 cvtpk(s[3][0], s[3][1]), cvtpk(s[3][2], s[3][3]) };
    short8 pa0 = __builtin_bit_cast(short8, p0);
    short8 pa1 = __builtin_bit_cast(short8, p1);

    // ---- PV: V fragments from LDS (permuted kv order matching pa) ----
#pragma unroll
    for (int db = 0; db < 4; ++db) {
      int d = db * 16 + lrow, sw = d & 7;
#pragma unroll
      for (int hk = 0; hk < 2; ++hk) {
        int b1 = 64 * hk + 8 * lkg;   // bytes of kv {hk*32+4lkg ..+4}
        int b2 = b1 + 32;             // kv {hk*32+16+4lkg ..+4}
        uint2 va = *(const uint2*)(sv + d * 128 + ((((b1 >> 4) ^ sw) << 4) | (b1 & 15)));
        uint2 vb = *(const uint2*)(sv + d * 128 + ((((b2 >> 4) ^ sw) << 4) | (b2 & 15)));
        uint4 uu = {va.x, va.y, vb.x, vb.y};
        short8 vf = __builtin_bit_cast(short8, uu);
        o[db] = mfma_bf16(hk ? pa1 : pa0, vf, o[db]);
      }
    }
    __syncthreads();   // staging of t+1 drained; all reads of buf[cur] done
  }

  // ---- epilogue: reduce lane-partial l, normalize, store ----
  l_ += __shfl_xor(l_, 16);
  l_ += __shfl_xor(l_, 32);
  int b = bh / 12, h = bh - b * 12;
  float nn[4];
  nn[0] = 1.0f / __shfl(l_, lkg * 4 + 0);
  nn[1] = 1.0f / __shfl(l_, lkg * 4 + 1);
  nn[2] = 1.0f / __shfl(l_, lkg * 4 + 2);
  nn[3] = 1.0f / __shfl(l_, lkg * 4 + 3);
#pragma unroll
  for (int i = 0; i < 4; ++i) {
    int qr = qw + lkg * 4 + i;
    u16* orow = og + ((size_t)(b * 2048 + qr)) * 768 + h * 64 + lrow;
    orow[0]  = f2bf(o[0][i] * nn[i]);
    orow[16] = f2bf(o[1][i] * nn[i]);
    orow[32] = f2bf(o[2][i] * nn[i]);
    orow[48] = f2bf(o[3][i] * nn[i]);
  }
}

// ---------- launch ----------
extern "C" void kernel_launch(void* const* d_in, const int* in_sizes, int n_in,
                              void* d_out, int out_size, void* d_ws, size_t ws_size,
                              hipStream_t stream) {
  const float* hs = (const float*)d_in[0];
  const float* wq = (const float*)d_in[1];
  const float* wk = (const float*)d_in[2];
  const float* wv = (const float*)d_in[3];
  const float* wo = (const float*)d_in[4];
  // d_in[5] (attn_mask) is exactly causal -1e9: implemented in-kernel.
  float* out = (float*)d_out;
  char* ws = (char*)d_ws;

  u16* hbf = (u16*)(ws);               // 4096x768 bf16          (6291456 B)
  u16* wbf = (u16*)(ws + 6291456);     // wq|wk|wv|wo bf16       (4718592 B)
  u16* qb  = (u16*)(ws + 11010048);    // [B,H,S,64] bf16 (pre-scaled, roped)
  u16* kb  = (u16*)(ws + 17301504);    // [B,H,S,64] bf16 (roped)
  u16* vtb = (u16*)(ws + 23592960);    // [B,H,64,S] bf16
  u16* ob  = (u16*)(ws + 29884416);    // [B,S,768]  bf16

  cvt_kernel<<<dim3(3072, 5), 256, 0, stream>>>(hs, wq, wk, wv, wo, hbf, wbf);
  gemm_bt<0><<<dim3(32, 18), 256, 0, stream>>>(hbf, wbf, qb, kb, vtb, nullptr);
  attn_fwd<<<dim3(768), 256, 0, stream>>>(qb, kb, vtb, ob);
  gemm_bt<1><<<dim3(32, 6), 256, 0, stream>>>(ob, wbf + 1769472, nullptr, nullptr, nullptr, out);
}

// Round 6
// 91.074 us; speedup vs baseline: 2.2958x; 1.0562x over previous
//
#include <hip/hip_runtime.h>

typedef unsigned short u16;
typedef short short8 __attribute__((ext_vector_type(8)));
typedef float f32x4 __attribute__((ext_vector_type(4)));

static_assert(sizeof(short8) == 16, "short8 must be 16B");

// ---------- helpers ----------
__device__ __forceinline__ u16 f2bf(float f) {
  unsigned u = __float_as_uint(f);
  u += 0x7FFFu + ((u >> 16) & 1u);   // RNE
  return (u16)(u >> 16);
}
__device__ __forceinline__ float bf2f(u16 h) { return __uint_as_float(((unsigned)h) << 16); }

__device__ __forceinline__ f32x4 mfma_bf16(short8 a, short8 b, f32x4 c) {
  return __builtin_amdgcn_mfma_f32_16x16x32_bf16(a, b, c, 0, 0, 0);
}

__device__ __forceinline__ void gload_lds16(const void* g, void* l) {
  __builtin_amdgcn_global_load_lds((__attribute__((address_space(1))) void*)g,
                                   (__attribute__((address_space(3))) void*)l, 16, 0, 0);
}

__device__ __forceinline__ float exp2v(float x) {
  float r; asm("v_exp_f32 %0, %1" : "=v"(r) : "v"(x)); return r;
}
__device__ __forceinline__ unsigned cvtpk(float lo, float hi) {
  unsigned r; asm("v_cvt_pk_bf16_f32 %0, %1, %2" : "=v"(r) : "v"(lo), "v"(hi)); return r;
}
__device__ __forceinline__ f32x4 vmax4(f32x4 a, f32x4 b) {
  f32x4 r;
  r[0] = fmaxf(a[0], b[0]); r[1] = fmaxf(a[1], b[1]);
  r[2] = fmaxf(a[2], b[2]); r[3] = fmaxf(a[3], b[3]);
  return r;
}

// ---------- fp32 -> bf16 conversion (hidden + 4 weights), flat grid ----------
__global__ __launch_bounds__(256) void cvt_kernel(
    const float* __restrict__ hs, const float* __restrict__ wq, const float* __restrict__ wk,
    const float* __restrict__ wv, const float* __restrict__ wo,
    u16* __restrict__ hbf, u16* __restrict__ wbf) {
  int i = blockIdx.x * 256 + threadIdx.x;    // < 1376256 uint2-units
  const float* src; u16* dst; int idx;
  if (i < 786432) {                          // hidden: 4096*768/4
    src = hs; dst = hbf; idx = i;
  } else {
    int j = i - 786432;
    int seg = j / 147456;                    // 0..3 (768*768/4 each)
    idx = j - seg * 147456;
    src = (seg == 0) ? wq : (seg == 1) ? wk : (seg == 2) ? wv : wo;
    dst = wbf + seg * 589824;
  }
  float4 v = ((const float4*)src)[idx];
  uint2 r;
  r.x = (unsigned)f2bf(v.x) | ((unsigned)f2bf(v.y) << 16);
  r.y = (unsigned)f2bf(v.z) | ((unsigned)f2bf(v.w) << 16);
  ((uint2*)dst)[idx] = r;
}

// ---------- GEMM: C(MxN) = A(MxK) * B(NxK)^T, bf16 in, m97-style ----------
// MODE 0: BM=128; QKV epilogue, fused RoPE (q,k) + q pre-scale by 0.125*log2e;
//         q,k -> [B,H,S,64], v -> transposed [B,H,64,S] (bf16)
// MODE 1: BM=64 (384 blocks, all-resident); fp32 epilogue -> fout (M x 768)
template <int MODE>
__global__ __launch_bounds__(256) void gemm_bt(
    const u16* __restrict__ A, const u16* __restrict__ Bm,
    u16* __restrict__ qb, u16* __restrict__ kb, u16* __restrict__ vtb,
    float* __restrict__ fout) {
  constexpr int MF = (MODE == 0) ? 4 : 2;   // m-frags per wave
  constexpr int BM = MF * 32;               // block rows
  __shared__ char sA[BM * 128];             // BM rows x 64 bf16 (XOR-swizzled slots)
  __shared__ char sB[16384];                // 128 rows x 64 bf16
  const int K = 768;
  const int t = threadIdx.x;
  const int lane = t & 63;
  const int w = t >> 6;              // wave 0..3
  const int wr = w >> 1, wc = w & 1; // 2x2 wave grid
  const int lrow = lane & 15, lkg = lane >> 4;
  const int arow0 = blockIdx.x * BM, brow0 = blockIdx.y * 128;

  f32x4 acc[MF][4];
  const f32x4 z4 = {0.f, 0.f, 0.f, 0.f};
#pragma unroll
  for (int m = 0; m < MF; ++m)
#pragma unroll
    for (int n = 0; n < 4; ++n) acc[m][n] = z4;

  const int srow = t >> 3;   // 0..31 (staging row within 32-row chunk)
  const int sslot = t & 7;   // physical 16B slot

  for (int kt = 0; kt < K; kt += 64) {
    __syncthreads();
#pragma unroll
    for (int it = 0; it < MF; ++it) {
      int r = it * 32 + srow;
      int ls = sslot ^ (r & 7);
      gload_lds16(A + (size_t)(arow0 + r) * K + (kt + ls * 8), sA + it * 4096 + w * 1024);
    }
#pragma unroll
    for (int it = 0; it < 4; ++it) {
      int r = it * 32 + srow;
      int ls = sslot ^ (r & 7);
      gload_lds16(Bm + (size_t)(brow0 + r) * K + (kt + ls * 8), sB + it * 4096 + w * 1024);
    }
    __syncthreads();
#pragma unroll
    for (int kk = 0; kk < 2; ++kk) {
      short8 af[MF], bfr[4];
#pragma unroll
      for (int m = 0; m < MF; ++m) {
        int row = wr * (BM / 2) + m * 16 + lrow;
        int ph = (kk * 4 + lkg) ^ (row & 7);
        af[m] = *(const short8*)(sA + row * 128 + ph * 16);
      }
#pragma unroll
      for (int n = 0; n < 4; ++n) {
        int row = wc * 64 + n * 16 + lrow;
        int ph = (kk * 4 + lkg) ^ (row & 7);
        bfr[n] = *(const short8*)(sB + row * 128 + ph * 16);
      }
#pragma unroll
      for (int m = 0; m < MF; ++m)
#pragma unroll
        for (int n = 0; n < 4; ++n) acc[m][n] = mfma_bf16(af[m], bfr[n], acc[m][n]);
    }
  }

  if (MODE == 1) {
#pragma unroll
    for (int m = 0; m < MF; ++m)
#pragma unroll
      for (int n = 0; n < 4; ++n)
#pragma unroll
        for (int i = 0; i < 4; ++i) {
          int row = arow0 + wr * (BM / 2) + m * 16 + lkg * 4 + i;
          int col = brow0 + wc * 64 + n * 16 + lrow;
          fout[(size_t)row * 768 + col] = acc[m][n][i];
        }
  } else {
    const int qsel = brow0 / 768;    // 0=q 1=k 2=v, uniform per block
    if (qsel < 2) {
      // fused RoPE: pairs (d, d+32) = (acc[m][n2], acc[m][n2+2]), d = n2*16+lrow
      u16* dst = qsel ? kb : qb;
      const float oscale = qsel ? 1.0f : 0.1803368801111244f;  // 0.125*log2(e) into q
      float fr[2];
      fr[0] = __expf(-0.2878231366242557f * (float)lrow);         // 10000^(-d/32)
      fr[1] = __expf(-0.2878231366242557f * (float)(16 + lrow));
      const int hh = ((brow0 - qsel * 768) >> 6) + wc;            // head index
#pragma unroll
      for (int m = 0; m < MF; ++m)
#pragma unroll
        for (int i = 0; i < 4; ++i) {
          int row = arow0 + wr * (BM / 2) + m * 16 + lkg * 4 + i;
          int b = row >> 11, s = row & 2047;
          size_t base = ((size_t)(b * 12 + hh) * 2048 + s) * 64;
#pragma unroll
          for (int n2 = 0; n2 < 2; ++n2) {
            float x1 = acc[m][n2][i], x2 = acc[m][n2 + 2][i];
            float th = (float)s * fr[n2];
            float sn, cs;
            __sincosf(th, &sn, &cs);
            dst[base + n2 * 16 + lrow]      = f2bf((x1 * cs - x2 * sn) * oscale);
            dst[base + 32 + n2 * 16 + lrow] = f2bf((x2 * cs + x1 * sn) * oscale);
          }
        }
    } else {
#pragma unroll
      for (int m = 0; m < MF; ++m)
#pragma unroll
        for (int n = 0; n < 4; ++n)
#pragma unroll
          for (int i = 0; i < 4; ++i) {
            int row = arow0 + wr * (BM / 2) + m * 16 + lkg * 4 + i;
            int col = brow0 + wc * 64 + n * 16 + lrow;
            int b = row >> 11, s = row & 2047;
            int oc = col - 1536, h = oc >> 6, d = oc & 63;
            vtb[((size_t)(b * 12 + h) * 64 + d) * 2048 + s] = f2bf(acc[m][n][i]);
          }
    }
  }
}

// ---------- causal flash attention v5.1 ----------
// 768 blocks = (head, 64 q-rows), 4 waves x 16 q-rows; niter = qc+1 uniform.
// K/V KVBLK=64 shared via LDS (async global_load_lds, XOR-swizzled), dbuf,
// one barrier/iter. Swapped QK^T, in-register softmax, defer-max, lane-partial
// l. Q pre-scaled by 0.125*log2e in GEMM. s_setprio around MFMA clusters (T5).
__global__ __launch_bounds__(256, 4) void attn_fwd(
    const u16* __restrict__ qg, const u16* __restrict__ kg,
    const u16* __restrict__ vtg, u16* __restrict__ og) {
  __shared__ __align__(16) char sm[32768];   // [2 bufs][ K 8KB | V 8KB ]
  const int lane = threadIdx.x & 63;
  const int w = threadIdx.x >> 6;            // 0..3
  const int lrow = lane & 15, lkg = lane >> 4;

  const int u = blockIdx.x;                  // 0..767
  const int xcd = u & 7, vv = u >> 3;        // heads pinned to XCDs; big-first
  const int bh = xcd * 3 + (vv % 3);
  const int qc = 31 - (vv / 3);              // 64-row q-chunk, qc=31 dispatched first
  const int qw = qc * 64 + w * 16;           // wave's first q-row
  const int niter = qc + 1;

  const u16* Q  = qg  + (size_t)bh * (2048 * 64);
  const u16* Kp = kg  + (size_t)bh * (2048 * 64);
  const u16* VT = vtg + (size_t)bh * (64 * 2048);

  short8 qf[2];
#pragma unroll
  for (int h = 0; h < 2; ++h)
    qf[h] = *(const short8*)(Q + (size_t)(qw + lrow) * 64 + h * 32 + lkg * 8);

  const f32x4 z4 = {0.f, 0.f, 0.f, 0.f};
  f32x4 o[4] = {z4, z4, z4, z4};
  float m_ = -1e30f, l_ = 0.f;

  // staging: wave w stages K rows [w*16,+16) and VT rows [w*16,+16)
  const int s_rl = lane >> 3;                // 0..7
  const int s_p  = lane & 7;                 // physical 16B slot
  auto STAGE = [&](int t, int b) {
    const int kv0 = t << 6;
    char* sk = sm + b * 16384;
    char* sv = sk + 8192;
    int r0 = w * 16 + s_rl, r1 = r0 + 8;
    gload_lds16(Kp + (size_t)(kv0 + r0) * 64 + ((s_p ^ (r0 & 7)) << 3), sk + w * 2048);
    gload_lds16(Kp + (size_t)(kv0 + r1) * 64 + ((s_p ^ (r1 & 7)) << 3), sk + w * 2048 + 1024);
    gload_lds16(VT + (size_t)r0 * 2048 + kv0 + ((s_p ^ (r0 & 7)) << 3), sv + w * 2048);
    gload_lds16(VT + (size_t)r1 * 2048 + kv0 + ((s_p ^ (r1 & 7)) << 3), sv + w * 2048 + 1024);
  };

  STAGE(0, 0);
  __syncthreads();

  for (int t = 0; t < niter; ++t) {
    const int kv0 = t << 6;
    const int cur = t & 1;
    if (t + 1 < niter) STAGE(t + 1, cur ^ 1);   // async; drains at the barrier

    const char* sk = sm + cur * 16384;
    const char* sv = sk + 8192;

    // ---- QK^T (swapped: A=K rows=kv, B=Q cols=q); scores already log2-scaled ----
    f32x4 s[4];
    __builtin_amdgcn_s_setprio(1);
#pragma unroll
    for (int kb = 0; kb < 4; ++kb) {
      int r = kb * 16 + lrow, sw = r & 7;
      short8 kf0 = *(const short8*)(sk + r * 128 + ((lkg ^ sw) << 4));
      short8 kf1 = *(const short8*)(sk + r * 128 + (((4 + lkg) ^ sw) << 4));
      s[kb] = mfma_bf16(kf0, qf[0], z4);
      s[kb] = mfma_bf16(kf1, qf[1], s[kb]);
    }
    __builtin_amdgcn_s_setprio(0);

    // ---- causal mask (only the diagonal tile) ----
    if (t == qc) {
      int qa = qw + lrow;
#pragma unroll
      for (int kb = 0; kb < 4; ++kb)
#pragma unroll
        for (int i = 0; i < 4; ++i)
          if (kv0 + kb * 16 + lkg * 4 + i > qa) s[kb][i] = -1e30f;
    }

    // ---- online softmax with defer-max ----
    f32x4 m03 = vmax4(vmax4(s[0], s[1]), vmax4(s[2], s[3]));
    float mt = fmaxf(fmaxf(m03[0], m03[1]), fmaxf(m03[2], m03[3]));
    mt = fmaxf(mt, __shfl_xor(mt, 16));
    mt = fmaxf(mt, __shfl_xor(mt, 32));
    if (__any(mt > m_ + 8.0f)) {               // rare rescale path
      float mn = fmaxf(m_, mt);
      float sclf = exp2v(m_ - mn);
      m_ = mn;
      l_ *= sclf;                              // l_ is per-lane partial
      float sc0 = __shfl(sclf, lkg * 4 + 0);
      float sc1 = __shfl(sclf, lkg * 4 + 1);
      float sc2 = __shfl(sclf, lkg * 4 + 2);
      float sc3 = __shfl(sclf, lkg * 4 + 3);
#pragma unroll
      for (int db = 0; db < 4; ++db) {
        o[db][0] *= sc0; o[db][1] *= sc1; o[db][2] *= sc2; o[db][3] *= sc3;
      }
    }
#pragma unroll
    for (int kb = 0; kb < 4; ++kb)
#pragma unroll
      for (int i = 0; i < 4; ++i) s[kb][i] = exp2v(s[kb][i] - m_);
    f32x4 st = (s[0] + s[1]) + (s[2] + s[3]);
    l_ += (st[0] + st[1]) + (st[2] + st[3]);   // partial over this lane's kv slots

    // ---- lane-local P pack (kv bijection j0..3 -> 4lkg+i, j4..7 -> 16+4lkg+i) ----
    uint4 p0 = { cvtpk(s[0][0], s[0][1]), cvtpk(s[0][2], s[0][3]),
                 cvtpk(s[1][0], s[1][1]), cvtpk(s[1][2], s[1][3]) };
    uint4 p1 = { cvtpk(s[2][0], s[2][1]), cvtpk(s[2][2], s[2][3]),
                 cvtpk(s[3][0], s[3][1]), cvtpk(s[3][2], s[3][3]) };
    short8 pa0 = __builtin_bit_cast(short8, p0);
    short8 pa1 = __builtin_bit_cast(short8, p1);

    // ---- PV: V fragments from LDS (permuted kv order matching pa) ----
    __builtin_amdgcn_s_setprio(1);
#pragma unroll
    for (int db = 0; db < 4; ++db) {
      int d = db * 16 + lrow, sw = d & 7;
#pragma unroll
      for (int hk = 0; hk < 2; ++hk) {
        int b1 = 64 * hk + 8 * lkg;   // bytes of kv {hk*32+4lkg ..+4}
        int b2 = b1 + 32;             // kv {hk*32+16+4lkg ..+4}
        uint2 va = *(const uint2*)(sv + d * 128 + ((((b1 >> 4) ^ sw) << 4) | (b1 & 15)));
        uint2 vb = *(const uint2*)(sv + d * 128 + ((((b2 >> 4) ^ sw) << 4) | (b2 & 15)));
        uint4 uu = {va.x, va.y, vb.x, vb.y};
        short8 vf = __builtin_bit_cast(short8, uu);
        o[db] = mfma_bf16(hk ? pa1 : pa0, vf, o[db]);
      }
    }
    __builtin_amdgcn_s_setprio(0);
    __syncthreads();   // staging of t+1 drained; all reads of buf[cur] done
  }

  // ---- epilogue: reduce lane-partial l, normalize, store ----
  l_ += __shfl_xor(l_, 16);
  l_ += __shfl_xor(l_, 32);
  int b = bh / 12, h = bh - b * 12;
  float nn[4];
  nn[0] = 1.0f / __shfl(l_, lkg * 4 + 0);
  nn[1] = 1.0f / __shfl(l_, lkg * 4 + 1);
  nn[2] = 1.0f / __shfl(l_, lkg * 4 + 2);
  nn[3] = 1.0f / __shfl(l_, lkg * 4 + 3);
#pragma unroll
  for (int i = 0; i < 4; ++i) {
    int qr = qw + lkg * 4 + i;
    u16* orow = og + ((size_t)(b * 2048 + qr)) * 768 + h * 64 + lrow;
    orow[0]  = f2bf(o[0][i] * nn[i]);
    orow[16] = f2bf(o[1][i] * nn[i]);
    orow[32] = f2bf(o[2][i] * nn[i]);
    orow[48] = f2bf(o[3][i] * nn[i]);
  }
}

// ---------- launch ----------
extern "C" void kernel_launch(void* const* d_in, const int* in_sizes, int n_in,
                              void* d_out, int out_size, void* d_ws, size_t ws_size,
                              hipStream_t stream) {
  const float* hs = (const float*)d_in[0];
  const float* wq = (const float*)d_in[1];
  const float* wk = (const float*)d_in[2];
  const float* wv = (const float*)d_in[3];
  const float* wo = (const float*)d_in[4];
  // d_in[5] (attn_mask) is exactly causal -1e9: implemented in-kernel.
  float* out = (float*)d_out;
  char* ws = (char*)d_ws;

  u16* hbf = (u16*)(ws);               // 4096x768 bf16          (6291456 B)
  u16* wbf = (u16*)(ws + 6291456);     // wq|wk|wv|wo bf16       (4718592 B)
  u16* qb  = (u16*)(ws + 11010048);    // [B,H,S,64] bf16 (pre-scaled, roped)
  u16* kb  = (u16*)(ws + 17301504);    // [B,H,S,64] bf16 (roped)
  u16* vtb = (u16*)(ws + 23592960);    // [B,H,64,S] bf16
  u16* ob  = (u16*)(ws + 29884416);    // [B,S,768]  bf16

  cvt_kernel<<<dim3(5376), 256, 0, stream>>>(hs, wq, wk, wv, wo, hbf, wbf);
  gemm_bt<0><<<dim3(32, 18), 256, 0, stream>>>(hbf, wbf, qb, kb, vtb, nullptr);
  attn_fwd<<<dim3(768), 256, 0, stream>>>(qb, kb, vtb, ob);
  gemm_bt<1><<<dim3(64, 6), 256, 0, stream>>>(ob, wbf + 1769472, nullptr, nullptr, nullptr, out);
}

// Round 7
// 81.615 us; speedup vs baseline: 2.5618x; 1.1159x over previous
//
#include <hip/hip_runtime.h>

typedef unsigned short u16;
typedef short short8 __attribute__((ext_vector_type(8)));
typedef float f32x4 __attribute__((ext_vector_type(4)));

static_assert(sizeof(short8) == 16, "short8 must be 16B");

// ---------- helpers ----------
__device__ __forceinline__ u16 f2bf(float f) {
  unsigned u = __float_as_uint(f);
  u += 0x7FFFu + ((u >> 16) & 1u);   // RNE
  return (u16)(u >> 16);
}
__device__ __forceinline__ float bf2f(u16 h) { return __uint_as_float(((unsigned)h) << 16); }

__device__ __forceinline__ f32x4 mfma_bf16(short8 a, short8 b, f32x4 c) {
  return __builtin_amdgcn_mfma_f32_16x16x32_bf16(a, b, c, 0, 0, 0);
}

__device__ __forceinline__ void gload_lds16(const void* g, void* l) {
  __builtin_amdgcn_global_load_lds((__attribute__((address_space(1))) void*)g,
                                   (__attribute__((address_space(3))) void*)l, 16, 0, 0);
}

__device__ __forceinline__ float exp2v(float x) {
  float r; asm("v_exp_f32 %0, %1" : "=v"(r) : "v"(x)); return r;
}
__device__ __forceinline__ unsigned cvtpk(float lo, float hi) {
  unsigned r; asm("v_cvt_pk_bf16_f32 %0, %1, %2" : "=v"(r) : "v"(lo), "v"(hi)); return r;
}
__device__ __forceinline__ f32x4 vmax4(f32x4 a, f32x4 b) {
  f32x4 r;
  r[0] = fmaxf(a[0], b[0]); r[1] = fmaxf(a[1], b[1]);
  r[2] = fmaxf(a[2], b[2]); r[3] = fmaxf(a[3], b[3]);
  return r;
}

// ---------- fp32 -> bf16 conversion (hidden + 4 weights), flat grid ----------
__global__ __launch_bounds__(256) void cvt_kernel(
    const float* __restrict__ hs, const float* __restrict__ wq, const float* __restrict__ wk,
    const float* __restrict__ wv, const float* __restrict__ wo,
    u16* __restrict__ hbf, u16* __restrict__ wbf) {
  int i = blockIdx.x * 256 + threadIdx.x;    // < 1376256 uint2-units
  const float* src; u16* dst; int idx;
  if (i < 786432) {                          // hidden: 4096*768/4
    src = hs; dst = hbf; idx = i;
  } else {
    int j = i - 786432;
    int seg = j / 147456;                    // 0..3 (768*768/4 each)
    idx = j - seg * 147456;
    src = (seg == 0) ? wq : (seg == 1) ? wk : (seg == 2) ? wv : wo;
    dst = wbf + seg * 589824;
  }
  float4 v = ((const float4*)src)[idx];
  uint2 r;
  r.x = (unsigned)f2bf(v.x) | ((unsigned)f2bf(v.y) << 16);
  r.y = (unsigned)f2bf(v.z) | ((unsigned)f2bf(v.w) << 16);
  ((uint2*)dst)[idx] = r;
}

// ---------- GEMM: C(MxN) = A(MxK) * B(NxK)^T, bf16 in ----------
// BM=64, BN=128, BK=64; double-buffered LDS (T3 2-phase: STAGE(t+1) || compute(t),
// one barrier/iter); bijective XCD swizzle (x-contiguous chunks per XCD).
// MODE 0: QKV epilogue, fused RoPE (q,k) + q pre-scale by 0.125*log2e;
//         q,k -> [B,H,S,64], v -> transposed [B,H,64,S] (bf16). grid 1152.
// MODE 1: fp32 epilogue -> fout row-major (M x 768). grid 384.
template <int MODE>
__global__ __launch_bounds__(256, 2) void gemm_bt(
    const u16* __restrict__ A, const u16* __restrict__ Bm,
    u16* __restrict__ qb, u16* __restrict__ kb, u16* __restrict__ vtb,
    float* __restrict__ fout) {
  __shared__ __align__(16) char sm[49152];   // 2 bufs x [A 8KB | B 16KB]
  const int K = 768, NK = 12;
  const int t = threadIdx.x;
  const int lane = t & 63;
  const int w = t >> 6;              // wave 0..3
  const int wr = w >> 1, wc = w & 1; // 2x2 wave grid: 32 rows x 64 cols each
  const int lrow = lane & 15, lkg = lane >> 4;

  // XCD-bijective decode: XCD k owns x-tiles [k*8, k*8+8), all y (B L2-resident)
  const int l = (MODE == 0) ? ((blockIdx.x & 7) * 144 + (blockIdx.x >> 3))
                            : ((blockIdx.x & 7) * 48 + (blockIdx.x >> 3));
  const int bx = (MODE == 0) ? (l / 18) : (l / 6);
  const int by = (MODE == 0) ? (l % 18) : (l % 6);
  const int arow0 = bx * 64, brow0 = by * 128;

  f32x4 acc[2][4];
  const f32x4 z4 = {0.f, 0.f, 0.f, 0.f};
#pragma unroll
  for (int m = 0; m < 2; ++m)
#pragma unroll
    for (int n = 0; n < 4; ++n) acc[m][n] = z4;

  const int srow = t >> 3;   // 0..31 (staging row within 32-row chunk)
  const int sslot = t & 7;   // physical 16B slot

  auto STAGE = [&](int ki, int b) {
    char* sA = sm + b * 24576;
    char* sB = sA + 8192;
    const int kt = ki * 64;
#pragma unroll
    for (int it = 0; it < 2; ++it) {
      int r = it * 32 + srow;
      int ls = sslot ^ (r & 7);
      gload_lds16(A + (size_t)(arow0 + r) * K + (kt + ls * 8), sA + it * 4096 + w * 1024);
    }
#pragma unroll
    for (int it = 0; it < 4; ++it) {
      int r = it * 32 + srow;
      int ls = sslot ^ (r & 7);
      gload_lds16(Bm + (size_t)(brow0 + r) * K + (kt + ls * 8), sB + it * 4096 + w * 1024);
    }
  };

  STAGE(0, 0);
  __syncthreads();

  for (int ki = 0; ki < NK; ++ki) {
    const int cur = ki & 1;
    if (ki + 1 < NK) STAGE(ki + 1, cur ^ 1);   // async; drains at the barrier
    const char* sA = sm + cur * 24576;
    const char* sB = sA + 8192;
#pragma unroll
    for (int kk = 0; kk < 2; ++kk) {
      short8 af[2], bfr[4];
#pragma unroll
      for (int m = 0; m < 2; ++m) {
        int row = wr * 32 + m * 16 + lrow;
        int ph = (kk * 4 + lkg) ^ (row & 7);
        af[m] = *(const short8*)(sA + row * 128 + ph * 16);
      }
#pragma unroll
      for (int n = 0; n < 4; ++n) {
        int row = wc * 64 + n * 16 + lrow;
        int ph = (kk * 4 + lkg) ^ (row & 7);
        bfr[n] = *(const short8*)(sB + row * 128 + ph * 16);
      }
#pragma unroll
      for (int m = 0; m < 2; ++m)
#pragma unroll
        for (int n = 0; n < 4; ++n) acc[m][n] = mfma_bf16(af[m], bfr[n], acc[m][n]);
    }
    __syncthreads();
  }

  if (MODE == 1) {
#pragma unroll
    for (int m = 0; m < 2; ++m)
#pragma unroll
      for (int n = 0; n < 4; ++n)
#pragma unroll
        for (int i = 0; i < 4; ++i) {
          int row = arow0 + wr * 32 + m * 16 + lkg * 4 + i;
          int col = brow0 + wc * 64 + n * 16 + lrow;
          fout[(size_t)row * 768 + col] = acc[m][n][i];
        }
  } else {
    const int qsel = brow0 / 768;    // 0=q 1=k 2=v, uniform per block
    if (qsel < 2) {
      // fused RoPE: pairs (d, d+32) = (acc[m][n2], acc[m][n2+2]), d = n2*16+lrow
      u16* dst = qsel ? kb : qb;
      const float oscale = qsel ? 1.0f : 0.1803368801111244f;  // 0.125*log2(e) into q
      float fr[2];
      fr[0] = __expf(-0.2878231366242557f * (float)lrow);         // 10000^(-d/32)
      fr[1] = __expf(-0.2878231366242557f * (float)(16 + lrow));
      const int hh = ((brow0 - qsel * 768) >> 6) + wc;            // head index
#pragma unroll
      for (int m = 0; m < 2; ++m)
#pragma unroll
        for (int i = 0; i < 4; ++i) {
          int row = arow0 + wr * 32 + m * 16 + lkg * 4 + i;
          int b = row >> 11, s = row & 2047;
          size_t base = ((size_t)(b * 12 + hh) * 2048 + s) * 64;
#pragma unroll
          for (int n2 = 0; n2 < 2; ++n2) {
            float x1 = acc[m][n2][i], x2 = acc[m][n2 + 2][i];
            float th = (float)s * fr[n2];
            float sn, cs;
            __sincosf(th, &sn, &cs);
            dst[base + n2 * 16 + lrow]      = f2bf((x1 * cs - x2 * sn) * oscale);
            dst[base + 32 + n2 * 16 + lrow] = f2bf((x2 * cs + x1 * sn) * oscale);
          }
        }
    } else {
#pragma unroll
      for (int m = 0; m < 2; ++m)
#pragma unroll
        for (int n = 0; n < 4; ++n)
#pragma unroll
          for (int i = 0; i < 4; ++i) {
            int row = arow0 + wr * 32 + m * 16 + lkg * 4 + i;
            int col = brow0 + wc * 64 + n * 16 + lrow;
            int b = row >> 11, s = row & 2047;
            int oc = col - 1536, h = oc >> 6, d = oc & 63;
            vtb[((size_t)(b * 12 + h) * 64 + d) * 2048 + s] = f2bf(acc[m][n][i]);
          }
    }
  }
}

// ---------- causal flash attention v5.1 (unchanged from r6) ----------
__global__ __launch_bounds__(256, 4) void attn_fwd(
    const u16* __restrict__ qg, const u16* __restrict__ kg,
    const u16* __restrict__ vtg, u16* __restrict__ og) {
  __shared__ __align__(16) char sm[32768];   // [2 bufs][ K 8KB | V 8KB ]
  const int lane = threadIdx.x & 63;
  const int w = threadIdx.x >> 6;            // 0..3
  const int lrow = lane & 15, lkg = lane >> 4;

  const int u = blockIdx.x;                  // 0..767
  const int xcd = u & 7, vv = u >> 3;        // heads pinned to XCDs; big-first
  const int bh = xcd * 3 + (vv % 3);
  const int qc = 31 - (vv / 3);              // 64-row q-chunk, qc=31 dispatched first
  const int qw = qc * 64 + w * 16;           // wave's first q-row
  const int niter = qc + 1;

  const u16* Q  = qg  + (size_t)bh * (2048 * 64);
  const u16* Kp = kg  + (size_t)bh * (2048 * 64);
  const u16* VT = vtg + (size_t)bh * (64 * 2048);

  short8 qf[2];
#pragma unroll
  for (int h = 0; h < 2; ++h)
    qf[h] = *(const short8*)(Q + (size_t)(qw + lrow) * 64 + h * 32 + lkg * 8);

  const f32x4 z4 = {0.f, 0.f, 0.f, 0.f};
  f32x4 o[4] = {z4, z4, z4, z4};
  float m_ = -1e30f, l_ = 0.f;

  // staging: wave w stages K rows [w*16,+16) and VT rows [w*16,+16)
  const int s_rl = lane >> 3;                // 0..7
  const int s_p  = lane & 7;                 // physical 16B slot
  auto STAGE = [&](int t, int b) {
    const int kv0 = t << 6;
    char* sk = sm + b * 16384;
    char* sv = sk + 8192;
    int r0 = w * 16 + s_rl, r1 = r0 + 8;
    gload_lds16(Kp + (size_t)(kv0 + r0) * 64 + ((s_p ^ (r0 & 7)) << 3), sk + w * 2048);
    gload_lds16(Kp + (size_t)(kv0 + r1) * 64 + ((s_p ^ (r1 & 7)) << 3), sk + w * 2048 + 1024);
    gload_lds16(VT + (size_t)r0 * 2048 + kv0 + ((s_p ^ (r0 & 7)) << 3), sv + w * 2048);
    gload_lds16(VT + (size_t)r1 * 2048 + kv0 + ((s_p ^ (r1 & 7)) << 3), sv + w * 2048 + 1024);
  };

  STAGE(0, 0);
  __syncthreads();

  for (int t = 0; t < niter; ++t) {
    const int kv0 = t << 6;
    const int cur = t & 1;
    if (t + 1 < niter) STAGE(t + 1, cur ^ 1);   // async; drains at the barrier

    const char* sk = sm + cur * 16384;
    const char* sv = sk + 8192;

    // ---- QK^T (swapped: A=K rows=kv, B=Q cols=q); scores already log2-scaled ----
    f32x4 s[4];
    __builtin_amdgcn_s_setprio(1);
#pragma unroll
    for (int kb = 0; kb < 4; ++kb) {
      int r = kb * 16 + lrow, sw = r & 7;
      short8 kf0 = *(const short8*)(sk + r * 128 + ((lkg ^ sw) << 4));
      short8 kf1 = *(const short8*)(sk + r * 128 + (((4 + lkg) ^ sw) << 4));
      s[kb] = mfma_bf16(kf0, qf[0], z4);
      s[kb] = mfma_bf16(kf1, qf[1], s[kb]);
    }
    __builtin_amdgcn_s_setprio(0);

    // ---- causal mask (only the diagonal tile) ----
    if (t == qc) {
      int qa = qw + lrow;
#pragma unroll
      for (int kb = 0; kb < 4; ++kb)
#pragma unroll
        for (int i = 0; i < 4; ++i)
          if (kv0 + kb * 16 + lkg * 4 + i > qa) s[kb][i] = -1e30f;
    }

    // ---- online softmax with defer-max ----
    f32x4 m03 = vmax4(vmax4(s[0], s[1]), vmax4(s[2], s[3]));
    float mt = fmaxf(fmaxf(m03[0], m03[1]), fmaxf(m03[2], m03[3]));
    mt = fmaxf(mt, __shfl_xor(mt, 16));
    mt = fmaxf(mt, __shfl_xor(mt, 32));
    if (__any(mt > m_ + 8.0f)) {               // rare rescale path
      float mn = fmaxf(m_, mt);
      float sclf = exp2v(m_ - mn);
      m_ = mn;
      l_ *= sclf;                              // l_ is per-lane partial
      float sc0 = __shfl(sclf, lkg * 4 + 0);
      float sc1 = __shfl(sclf, lkg * 4 + 1);
      float sc2 = __shfl(sclf, lkg * 4 + 2);
      float sc3 = __shfl(sclf, lkg * 4 + 3);
#pragma unroll
      for (int db = 0; db < 4; ++db) {
        o[db][0] *= sc0; o[db][1] *= sc1; o[db][2] *= sc2; o[db][3] *= sc3;
      }
    }
#pragma unroll
    for (int kb = 0; kb < 4; ++kb)
#pragma unroll
      for (int i = 0; i < 4; ++i) s[kb][i] = exp2v(s[kb][i] - m_);
    f32x4 st = (s[0] + s[1]) + (s[2] + s[3]);
    l_ += (st[0] + st[1]) + (st[2] + st[3]);   // partial over this lane's kv slots

    // ---- lane-local P pack (kv bijection j0..3 -> 4lkg+i, j4..7 -> 16+4lkg+i) ----
    uint4 p0 = { cvtpk(s[0][0], s[0][1]), cvtpk(s[0][2], s[0][3]),
                 cvtpk(s[1][0], s[1][1]), cvtpk(s[1][2], s[1][3]) };
    uint4 p1 = { cvtpk(s[2][0], s[2][1]), cvtpk(s[2][2], s[2][3]),
                 cvtpk(s[3][0], s[3][1]), cvtpk(s[3][2], s[3][3]) };
    short8 pa0 = __builtin_bit_cast(short8, p0);
    short8 pa1 = __builtin_bit_cast(short8, p1);

    // ---- PV: V fragments from LDS (permuted kv order matching pa) ----
    __builtin_amdgcn_s_setprio(1);
#pragma unroll
    for (int db = 0; db < 4; ++db) {
      int d = db * 16 + lrow, sw = d & 7;
#pragma unroll
      for (int hk = 0; hk < 2; ++hk) {
        int b1 = 64 * hk + 8 * lkg;   // bytes of kv {hk*32+4lkg ..+4}
        int b2 = b1 + 32;             // kv {hk*32+16+4lkg ..+4}
        uint2 va = *(const uint2*)(sv + d * 128 + ((((b1 >> 4) ^ sw) << 4) | (b1 & 15)));
        uint2 vb = *(const uint2*)(sv + d * 128 + ((((b2 >> 4) ^ sw) << 4) | (b2 & 15)));
        uint4 uu = {va.x, va.y, vb.x, vb.y};
        short8 vf = __builtin_bit_cast(short8, uu);
        o[db] = mfma_bf16(hk ? pa1 : pa0, vf, o[db]);
      }
    }
    __builtin_amdgcn_s_setprio(0);
    __syncthreads();   // staging of t+1 drained; all reads of buf[cur] done
  }

  // ---- epilogue: reduce lane-partial l, normalize, store ----
  l_ += __shfl_xor(l_, 16);
  l_ += __shfl_xor(l_, 32);
  int b = bh / 12, h = bh - b * 12;
  float nn[4];
  nn[0] = 1.0f / __shfl(l_, lkg * 4 + 0);
  nn[1] = 1.0f / __shfl(l_, lkg * 4 + 1);
  nn[2] = 1.0f / __shfl(l_, lkg * 4 + 2);
  nn[3] = 1.0f / __shfl(l_, lkg * 4 + 3);
#pragma unroll
  for (int i = 0; i < 4; ++i) {
    int qr = qw + lkg * 4 + i;
    u16* orow = og + ((size_t)(b * 2048 + qr)) * 768 + h * 64 + lrow;
    orow[0]  = f2bf(o[0][i] * nn[i]);
    orow[16] = f2bf(o[1][i] * nn[i]);
    orow[32] = f2bf(o[2][i] * nn[i]);
    orow[48] = f2bf(o[3][i] * nn[i]);
  }
}

// ---------- launch ----------
extern "C" void kernel_launch(void* const* d_in, const int* in_sizes, int n_in,
                              void* d_out, int out_size, void* d_ws, size_t ws_size,
                              hipStream_t stream) {
  const float* hs = (const float*)d_in[0];
  const float* wq = (const float*)d_in[1];
  const float* wk = (const float*)d_in[2];
  const float* wv = (const float*)d_in[3];
  const float* wo = (const float*)d_in[4];
  // d_in[5] (attn_mask) is exactly causal -1e9: implemented in-kernel.
  float* out = (float*)d_out;
  char* ws = (char*)d_ws;

  u16* hbf = (u16*)(ws);               // 4096x768 bf16          (6291456 B)
  u16* wbf = (u16*)(ws + 6291456);     // wq|wk|wv|wo bf16       (4718592 B)
  u16* qb  = (u16*)(ws + 11010048);    // [B,H,S,64] bf16 (pre-scaled, roped)
  u16* kb  = (u16*)(ws + 17301504);    // [B,H,S,64] bf16 (roped)
  u16* vtb = (u16*)(ws + 23592960);    // [B,H,64,S] bf16
  u16* ob  = (u16*)(ws + 29884416);    // [B,S,768]  bf16

  cvt_kernel<<<dim3(5376), 256, 0, stream>>>(hs, wq, wk, wv, wo, hbf, wbf);
  gemm_bt<0><<<dim3(1152), 256, 0, stream>>>(hbf, wbf, qb, kb, vtb, nullptr);
  attn_fwd<<<dim3(768), 256, 0, stream>>>(qb, kb, vtb, ob);
  gemm_bt<1><<<dim3(384), 256, 0, stream>>>(ob, wbf + 1769472, nullptr, nullptr, nullptr, out);
}